// Round 5
// baseline (586.128 us; speedup 1.0000x reference)
//
#include <hip/hip_runtime.h>
#include <math.h>

#define BB 64
#define NN 8192
#define LL 64
#define KK 20
#define TILE 128
#define NT 8        // tiles per block
#define CHUNKS 8    // blocks per batch entry: CHUNKS*NT*TILE == NN (512 blocks = 2/CU exact)
#define ZS 68       // z_s row stride (floats): 272 B, 16B-aligned, bank-rotated
#define PS 132      // pt row stride: rows are 128 wide (one slot per tile row)
#define AS 132      // aug row stride: 33 granules of 16B, odd -> conflict-free col access
#define TS 68       // iaT row stride

// ---------------------------------------------------------------------------
// ws layout (floats):
//   IA   : [64*64]            @ 0
//   M    : [64*64]            @ 4096
//   bias : [B*K]              @ 8192
//   nk   : [B*K]              @ 9472
//   macc : [B*K*L]            @ 10752
// ---------------------------------------------------------------------------

// IA = I - A ; M = inv(I + IA @ IA^T) via Gauss-Jordan (SPD, no pivoting).
// Conflict-free layout: iaT transposed (lane-varying col), aug with odd
// 16B-granule stride (row-per-lane access spreads all 32 banks).
__global__ __launch_bounds__(256) void k_setup(const float* __restrict__ A,
                                               float* __restrict__ IA,
                                               float* __restrict__ M) {
    __shared__ __align__(16) float iaT[64][TS];
    __shared__ __align__(16) float aug[64][AS];
    __shared__ __align__(16) float prow[AS];
    int t = threadIdx.x;
    // load A coalesced; emit IA (global) and iaT (LDS, transposed)
    for (int i = t; i < 4096; i += 256) {
        int r = i >> 6, c = i & 63;
        float v = (r == c ? 1.0f : 0.0f) - A[i];
        IA[i] = v;
        iaT[c][r] = v;
    }
    __syncthreads();
    // S = I + IA·IAᵀ: thread computes a 4x4 block; S[r][c] = δ + Σ_l iaT[l][r]·iaT[l][c]
    {
        int r0 = (t >> 4) << 2;     // 0,4,...,60
        int c0 = (t & 15) << 2;     // 0,4,...,60
        float s[4][4];
        #pragma unroll
        for (int a = 0; a < 4; ++a)
            #pragma unroll
            for (int bq = 0; bq < 4; ++bq) s[a][bq] = 0.f;
        for (int l = 0; l < 64; ++l) {
            float4 u = *(const float4*)&iaT[l][r0];
            float4 v = *(const float4*)&iaT[l][c0];
            float uu[4] = {u.x, u.y, u.z, u.w};
            float vv[4] = {v.x, v.y, v.z, v.w};
            #pragma unroll
            for (int a = 0; a < 4; ++a)
                #pragma unroll
                for (int bq = 0; bq < 4; ++bq) s[a][bq] += uu[a] * vv[bq];
        }
        #pragma unroll
        for (int a = 0; a < 4; ++a) {
            int r = r0 + a;
            float4 w;
            w.x = s[a][0] + (r == c0 + 0 ? 1.f : 0.f);
            w.y = s[a][1] + (r == c0 + 1 ? 1.f : 0.f);
            w.z = s[a][2] + (r == c0 + 2 ? 1.f : 0.f);
            w.w = s[a][3] + (r == c0 + 3 ? 1.f : 0.f);
            *(float4*)&aug[r][c0] = w;
            float4 id;
            id.x = (r == c0 + 0 ? 1.f : 0.f);
            id.y = (r == c0 + 1 ? 1.f : 0.f);
            id.z = (r == c0 + 2 ? 1.f : 0.f);
            id.w = (r == c0 + 3 ? 1.f : 0.f);
            *(float4*)&aug[r][64 + c0] = id;
        }
    }
    __syncthreads();
    // Gauss-Jordan: thread = (row r, col-quarter g); 2 barriers per pivot.
    int r = t & 63;
    int g = t >> 6;
    for (int k = 0; k < 64; ++k) {
        float pivinv = 1.0f / aug[k][k];
        float f = aug[r][k];
        if (r == k) {   // stage normalized pivot row into prow (no aug writes)
            for (int c4 = g; c4 <= 32; c4 += 4) {
                float4 v = *(const float4*)&aug[k][c4 * 4];
                v.x *= pivinv; v.y *= pivinv; v.z *= pivinv; v.w *= pivinv;
                *(float4*)&prow[c4 * 4] = v;
            }
        }
        __syncthreads();
        if (r != k) {
            for (int c4 = g; c4 <= 32; c4 += 4) {
                float4 p = *(const float4*)&prow[c4 * 4];
                float4 v = *(const float4*)&aug[r][c4 * 4];
                v.x -= f * p.x; v.y -= f * p.y; v.z -= f * p.z; v.w -= f * p.w;
                *(float4*)&aug[r][c4 * 4] = v;
            }
        } else {
            for (int c4 = g; c4 <= 32; c4 += 4)
                *(float4*)&aug[r][c4 * 4] = *(const float4*)&prow[c4 * 4];
        }
        __syncthreads();
    }
    for (int i = t; i < 4096; i += 256) {
        int rr = i >> 6, c = i & 63;
        M[i] = aug[rr][64 + c];
    }
}

// Per (b,k): mean = z[b, idx, :] @ M ; write bias; zero accumulators.
__global__ __launch_bounds__(64) void k_init(const float* __restrict__ z,
                                             const int* __restrict__ idxs,
                                             const float* __restrict__ M,
                                             const float* __restrict__ IA,
                                             float* __restrict__ out_mean,
                                             float* __restrict__ bias,
                                             float* __restrict__ nk,
                                             float* __restrict__ macc) {
    int k = blockIdx.x, b = blockIdx.y;
    int l = threadIdx.x;
    int bk = b * KK + k;
    __shared__ float srow[64];
    __shared__ float smean[64];
    int idx = idxs[bk];
    srow[l] = z[((size_t)b * NN + idx) * LL + l];
    __syncthreads();
    float nm = 0.f;
    #pragma unroll 8
    for (int m = 0; m < 64; ++m) nm += srow[m] * M[m * 64 + l];
    out_mean[(size_t)bk * LL + l] = nm;
    smean[l] = nm;
    __syncthreads();
    float cm = 0.f;
    #pragma unroll 8
    for (int m = 0; m < 64; ++m) cm += smean[m] * IA[m * 64 + l];
    float sqm = nm * nm;
    float sqc = cm * cm;
    for (int off = 32; off > 0; off >>= 1) {
        sqm += __shfl_down(sqm, off);
        sqc += __shfl_down(sqc, off);
    }
    if (l == 0) {
        bias[bk] = logf(1.0f / KK) - 0.5f * (sqm + sqc);
        nk[bk] = 0.f;
    }
    macc[(size_t)bk * LL + l] = 0.f;
}

// Fused EM pass, persistent-chunk version.
// Grid: (CHUNKS, BB) x 256 threads. Each block handles NT tiles of 128 rows.
__global__ __launch_bounds__(256, 4) void k_empass(const float* __restrict__ z,
                                                   const float* __restrict__ mean,
                                                   const float* __restrict__ bias,
                                                   float* __restrict__ nk,
                                                   float* __restrict__ macc) {
    __shared__ __align__(16) float z_s[TILE][ZS];
    __shared__ __align__(16) float mean_s[KK][ZS];
    __shared__ __align__(16) float pt[KK][PS];
    __shared__ float bias_s[KK];
    __shared__ float nkred[4][KK];
    int t = threadIdx.x;
    int lane = t & 63;
    int q = t >> 6;             // wave id 0..3
    int j = lane & 31;          // row-in-wave
    int h = lane >> 5;          // k half: 0 -> k 0..9, 1 -> k 10..19
    int myrow = q * 32 + j;
    int b = blockIdx.y;
    size_t zbase = ((size_t)b * NN + (size_t)blockIdx.x * (TILE * NT)) * LL;

    for (int i = t; i < KK * LL; i += 256)
        mean_s[i >> 6][i & 63] = mean[(size_t)b * KK * LL + i];
    if (t < KK) bias_s[t] = bias[b * KK + t];

    const float4* zg = (const float4*)(z + zbase);

    float pacc[KK];
    #pragma unroll
    for (int k = 0; k < KK; ++k) pacc[k] = 0.f;
    float nkp[10];
    #pragma unroll
    for (int i = 0; i < 10; ++i) nkp[i] = 0.f;

    for (int tt = 0; tt < NT; ++tt) {
        if (tt > 0) __syncthreads();   // protect z_s/pt overwrite vs prev phase B
        // ---- stage tile tt: global -> LDS (8 float4 per thread) ----
        #pragma unroll
        for (int u = 0; u < 8; ++u) {
            float4 v = zg[tt * 2048 + u * 256 + t];
            int f = u * 256 + t;
            *(float4*)&z_s[f >> 4][(f & 15) * 4] = v;
        }
        __syncthreads();
        // ---- phase A: logits + softmax, in registers ----
        float lg[10];
        #pragma unroll
        for (int i = 0; i < 10; ++i) lg[i] = bias_s[h * 10 + i];
        #pragma unroll 2
        for (int c = 0; c < 64; c += 8) {
            float4 a0 = *(const float4*)&z_s[myrow][c];
            float4 a1 = *(const float4*)&z_s[myrow][c + 4];
            #pragma unroll
            for (int i = 0; i < 10; ++i) {
                const float* mrow = mean_s[h * 10 + i];
                float4 m0 = *(const float4*)&mrow[c];
                float4 m1 = *(const float4*)&mrow[c + 4];
                lg[i] += a0.x * m0.x + a0.y * m0.y + a0.z * m0.z + a0.w * m0.w
                       + a1.x * m1.x + a1.y * m1.y + a1.z * m1.z + a1.w * m1.w;
            }
        }
        float mx = lg[0];
        #pragma unroll
        for (int i = 1; i < 10; ++i) mx = fmaxf(mx, lg[i]);
        mx = fmaxf(mx, __shfl_xor(mx, 32));
        float s = 0.f;
        #pragma unroll
        for (int i = 0; i < 10; ++i) { lg[i] = __expf(lg[i] - mx); s += lg[i]; }
        s += __shfl_xor(s, 32);
        float invs = 1.0f / s;
        #pragma unroll
        for (int i = 0; i < 10; ++i) {
            lg[i] *= invs;           // posterior
            nkp[i] += lg[i];
            pt[h * 10 + i][myrow] = lg[i];
        }
        __syncthreads();
        // ---- phase B: wave q accumulates rows q*32..+31, lane = column ----
        int rb = q * 32;
        #pragma unroll 2
        for (int r = rb; r < rb + 32; r += 4) {
            float zv0 = z_s[r][lane];
            float zv1 = z_s[r + 1][lane];
            float zv2 = z_s[r + 2][lane];
            float zv3 = z_s[r + 3][lane];
            #pragma unroll
            for (int k = 0; k < KK; ++k) {
                float4 p = *(const float4*)&pt[k][r];
                pacc[k] += p.x * zv0 + p.y * zv1 + p.z * zv2 + p.w * zv3;
            }
        }
    }
    __syncthreads();   // all phase-B reads of z_s done before red reuse

    // ---- cross-wave reduce (reuse z_s region), single atomic per slot ----
    float* red = &z_s[0][0];    // 4*20*64 = 5120 floats <= 128*68
    #pragma unroll
    for (int k = 0; k < KK; ++k) red[(q * KK + k) * 64 + lane] = pacc[k];
    #pragma unroll
    for (int off = 16; off >= 1; off >>= 1) {
        #pragma unroll
        for (int i = 0; i < 10; ++i) nkp[i] += __shfl_down(nkp[i], off);
    }
    if (j == 0) {
        #pragma unroll
        for (int i = 0; i < 10; ++i) nkred[q][h * 10 + i] = nkp[i];
    }
    __syncthreads();
    for (int idx = t; idx < KK * 64; idx += 256) {
        int k = idx >> 6, l = idx & 63;
        float sum = red[k * 64 + l] + red[(KK + k) * 64 + l]
                  + red[(2 * KK + k) * 64 + l] + red[(3 * KK + k) * 64 + l];
        atomicAdd(&macc[((size_t)b * KK + k) * LL + l], sum);
    }
    if (t < KK) {
        float sum = nkred[0][t] + nkred[1][t] + nkred[2][t] + nkred[3][t];
        atomicAdd(&nk[b * KK + t], sum);
    }
}

// Per (b,k): pi = Nk/N, mean = (macc/Nk) @ M, bias for next iter, re-zero acc.
__global__ __launch_bounds__(64) void k_final(const float* __restrict__ Mm,
                                              const float* __restrict__ IA,
                                              float* __restrict__ nk,
                                              float* __restrict__ macc,
                                              float* __restrict__ bias,
                                              float* __restrict__ out_pi,
                                              float* __restrict__ out_mean,
                                              float* __restrict__ out_trace) {
    int k = blockIdx.x, b = blockIdx.y;
    int l = threadIdx.x;
    int bk = b * KK + k;
    __shared__ float sraw[64];
    __shared__ float smean[64];
    float Nk = nk[bk];
    if (Nk == 0.f) Nk = 1e-22f;
    float pi = Nk / (float)NN;
    float raw = macc[(size_t)bk * LL + l] / Nk;
    sraw[l] = raw;
    __syncthreads();
    float nm = 0.f;
    #pragma unroll 8
    for (int m = 0; m < 64; ++m) nm += sraw[m] * Mm[m * 64 + l];
    out_mean[(size_t)bk * LL + l] = nm;
    smean[l] = nm;
    __syncthreads();
    float cm = 0.f;
    #pragma unroll 8
    for (int m = 0; m < 64; ++m) cm += smean[m] * IA[m * 64 + l];
    float sqm = nm * nm;
    float sqc = cm * cm;
    for (int off = 32; off > 0; off >>= 1) {
        sqm += __shfl_down(sqm, off);
        sqc += __shfl_down(sqc, off);
    }
    if (l == 0) {
        bias[bk] = logf(pi) - 0.5f * (sqm + sqc);
        out_pi[bk] = pi;
        out_trace[bk] = 1.0f;
        nk[bk] = 0.f;
    }
    macc[(size_t)bk * LL + l] = 0.f;
}

extern "C" void kernel_launch(void* const* d_in, const int* in_sizes, int n_in,
                              void* d_out, int out_size, void* d_ws, size_t ws_size,
                              hipStream_t stream) {
    const float* z = (const float*)d_in[0];
    const float* A = (const float*)d_in[1];
    const int* idxs = (const int*)d_in[2];

    float* out_pi = (float*)d_out;
    float* out_mean = out_pi + BB * KK;
    float* out_trace = out_mean + (size_t)BB * KK * LL;

    float* ws = (float*)d_ws;
    float* IA = ws;
    float* M = ws + 4096;
    float* bias = ws + 8192;
    float* nk = ws + 9472;
    float* macc = ws + 10752;

    k_setup<<<1, 256, 0, stream>>>(A, IA, M);
    k_init<<<dim3(KK, BB), 64, 0, stream>>>(z, idxs, M, IA, out_mean, bias, nk, macc);
    for (int it = 0; it < 5; ++it) {
        k_empass<<<dim3(CHUNKS, BB), 256, 0, stream>>>(z, out_mean, bias, nk, macc);
        k_final<<<dim3(KK, BB), 64, 0, stream>>>(M, IA, nk, macc, bias, out_pi, out_mean, out_trace);
    }
}

// Round 6
// 457.709 us; speedup vs baseline: 1.2806x; 1.2806x over previous
//
#include <hip/hip_runtime.h>
#include <math.h>

#define BB 64
#define NN 8192
#define LL 64
#define KK 20
#define TILE 128
#define NT 8        // tiles per block
#define CHUNKS 8    // blocks per batch entry: CHUNKS*NT*TILE == NN
#define ZSB 72      // zh/zl/mh/ml row stride (ushorts): 144 B = 9 granules (odd)
#define PTS 28      // pt row stride (floats): 112 B, 16B-aligned, read wave-uniform
#define AS 132      // aug row stride (floats)
#define TS 68       // iaT row stride

typedef float f32x4 __attribute__((ext_vector_type(4)));
typedef short s16x8 __attribute__((ext_vector_type(8)));
typedef unsigned short u16x4 __attribute__((ext_vector_type(4)));

#define MFMA_BF16 __builtin_amdgcn_mfma_f32_16x16x32_bf16

__device__ __forceinline__ unsigned short f2bf(float f) {   // RNE fp32->bf16
    unsigned int u = __float_as_uint(f);
    u += 0x7fffu + ((u >> 16) & 1u);
    return (unsigned short)(u >> 16);
}
__device__ __forceinline__ float bf2f(unsigned short h) {
    return __uint_as_float(((unsigned int)h) << 16);
}

// ---------------------------------------------------------------------------
// ws layout (floats): IA @0, M @4096, bias @8192, nk @9472, macc @10752
// ---------------------------------------------------------------------------

// IA = I - A ; M = inv(I + IA @ IA^T), Gauss-Jordan (SPD, no pivoting).
// Thread owns (row r = t&63, contiguous 32-col block g = t>>6); fully
// unrolled 8x float4 bodies so LDS latency overlaps; prow staging keeps the
// 2-barrier/pivot structure race-free.
__global__ __launch_bounds__(256) void k_setup(const float* __restrict__ A,
                                               float* __restrict__ IA,
                                               float* __restrict__ M) {
    __shared__ __align__(16) float iaT[64][TS];
    __shared__ __align__(16) float aug[64][AS];
    __shared__ __align__(16) float prow[AS];
    int t = threadIdx.x;
    for (int i = t; i < 4096; i += 256) {
        int r = i >> 6, c = i & 63;
        float v = (r == c ? 1.0f : 0.0f) - A[i];
        IA[i] = v;
        iaT[c][r] = v;
    }
    __syncthreads();
    {   // S = I + IA·IAᵀ, 4x4 blocks per thread
        int r0 = (t >> 4) << 2;
        int c0 = (t & 15) << 2;
        float s[4][4];
        #pragma unroll
        for (int a = 0; a < 4; ++a)
            #pragma unroll
            for (int bq = 0; bq < 4; ++bq) s[a][bq] = 0.f;
        for (int l = 0; l < 64; ++l) {
            float4 u = *(const float4*)&iaT[l][r0];
            float4 v = *(const float4*)&iaT[l][c0];
            float uu[4] = {u.x, u.y, u.z, u.w};
            float vv[4] = {v.x, v.y, v.z, v.w};
            #pragma unroll
            for (int a = 0; a < 4; ++a)
                #pragma unroll
                for (int bq = 0; bq < 4; ++bq) s[a][bq] += uu[a] * vv[bq];
        }
        #pragma unroll
        for (int a = 0; a < 4; ++a) {
            int r = r0 + a;
            float4 w;
            w.x = s[a][0] + (r == c0 + 0 ? 1.f : 0.f);
            w.y = s[a][1] + (r == c0 + 1 ? 1.f : 0.f);
            w.z = s[a][2] + (r == c0 + 2 ? 1.f : 0.f);
            w.w = s[a][3] + (r == c0 + 3 ? 1.f : 0.f);
            *(float4*)&aug[r][c0] = w;
            float4 id;
            id.x = (r == c0 + 0 ? 1.f : 0.f);
            id.y = (r == c0 + 1 ? 1.f : 0.f);
            id.z = (r == c0 + 2 ? 1.f : 0.f);
            id.w = (r == c0 + 3 ? 1.f : 0.f);
            *(float4*)&aug[r][64 + c0] = id;
        }
    }
    __syncthreads();
    int r = t & 63;
    int cbase = (t >> 6) * 32;
    for (int k = 0; k < 64; ++k) {
        float pivinv = 1.0f / aug[k][k];
        float f = aug[r][k];
        if (r == k) {
            #pragma unroll
            for (int i = 0; i < 8; ++i) {
                float4 v = *(const float4*)&aug[k][cbase + 4 * i];
                v.x *= pivinv; v.y *= pivinv; v.z *= pivinv; v.w *= pivinv;
                *(float4*)&prow[cbase + 4 * i] = v;
            }
        }
        __syncthreads();
        if (r != k) {
            #pragma unroll
            for (int i = 0; i < 8; ++i) {
                float4 p = *(const float4*)&prow[cbase + 4 * i];
                float4 v = *(const float4*)&aug[r][cbase + 4 * i];
                v.x -= f * p.x; v.y -= f * p.y; v.z -= f * p.z; v.w -= f * p.w;
                *(float4*)&aug[r][cbase + 4 * i] = v;
            }
        } else {
            #pragma unroll
            for (int i = 0; i < 8; ++i)
                *(float4*)&aug[k][cbase + 4 * i] = *(const float4*)&prow[cbase + 4 * i];
        }
        __syncthreads();
    }
    for (int i = t; i < 4096; i += 256) {
        int rr = i >> 6, c = i & 63;
        M[i] = aug[rr][64 + c];
    }
}

// Per (b,k): mean = z[b, idx, :] @ M ; write bias; zero accumulators.
__global__ __launch_bounds__(64) void k_init(const float* __restrict__ z,
                                             const int* __restrict__ idxs,
                                             const float* __restrict__ M,
                                             const float* __restrict__ IA,
                                             float* __restrict__ out_mean,
                                             float* __restrict__ bias,
                                             float* __restrict__ nk,
                                             float* __restrict__ macc) {
    int k = blockIdx.x, b = blockIdx.y;
    int l = threadIdx.x;
    int bk = b * KK + k;
    __shared__ float srow[64];
    __shared__ float smean[64];
    int idx = idxs[bk];
    srow[l] = z[((size_t)b * NN + idx) * LL + l];
    __syncthreads();
    float nm = 0.f;
    #pragma unroll 8
    for (int m = 0; m < 64; ++m) nm += srow[m] * M[m * 64 + l];
    out_mean[(size_t)bk * LL + l] = nm;
    smean[l] = nm;
    __syncthreads();
    float cm = 0.f;
    #pragma unroll 8
    for (int m = 0; m < 64; ++m) cm += smean[m] * IA[m * 64 + l];
    float sqm = nm * nm;
    float sqc = cm * cm;
    for (int off = 32; off > 0; off >>= 1) {
        sqm += __shfl_down(sqm, off);
        sqc += __shfl_down(sqc, off);
    }
    if (l == 0) {
        bias[bk] = logf(1.0f / KK) - 0.5f * (sqm + sqc);
        nk[bk] = 0.f;
    }
    macc[(size_t)bk * LL + l] = 0.f;
}

// Fused EM pass. Phase A = MFMA bf16 hi/lo split logits + in-register
// softmax; phase B = VALU column accumulate (z-hi). Persistent chunks.
__global__ __launch_bounds__(256, 2) void k_empass(const float* __restrict__ z,
                                                   const float* __restrict__ mean,
                                                   const float* __restrict__ bias,
                                                   float* __restrict__ nk,
                                                   float* __restrict__ macc) {
    __shared__ __align__(16) unsigned short zhl[2][TILE][ZSB];   // hi, lo planes
    __shared__ __align__(16) unsigned short mhl[2][32][ZSB];     // mean hi/lo, rows 20-31 zero
    __shared__ __align__(16) float pt[TILE][PTS];                // posteriors [row][k]
    __shared__ float bias_s[KK];
    __shared__ float nkred[4][KK];
    int t = threadIdx.x;
    int lane = t & 63;
    int q = t >> 6;             // wave id 0..3, owns rows q*32..q*32+31
    int ln = lane & 15;         // k-col within MFMA tile / row-in-tile
    int lg4 = lane >> 4;        // lane group 0..3
    int b = blockIdx.y;
    size_t zbase = ((size_t)b * NN + (size_t)blockIdx.x * (TILE * NT)) * LL;

    // stage mean (split hi/lo) + zero pad rows + bias
    for (int i = t; i < KK * LL; i += 256) {
        float f = mean[(size_t)b * KK * LL + i];
        int k = i >> 6, c = i & 63;
        unsigned short h = f2bf(f);
        mhl[0][k][c] = h;
        mhl[1][k][c] = f2bf(f - bf2f(h));
    }
    for (int i = 20 * ZSB + t; i < 32 * ZSB; i += 256) {
        (&mhl[0][0][0])[i] = 0;
        (&mhl[1][0][0])[i] = 0;
    }
    if (t < KK) bias_s[t] = bias[b * KK + t];
    __syncthreads();
    float bias0 = bias_s[ln];
    float bias1 = (ln < 4) ? bias_s[16 + ln] : 0.f;

    const float4* zg = (const float4*)(z + zbase);
    float pacc[KK];
    #pragma unroll
    for (int k = 0; k < KK; ++k) pacc[k] = 0.f;
    float nk0 = 0.f, nk1 = 0.f;

    for (int tt = 0; tt < NT; ++tt) {
        if (tt > 0) __syncthreads();   // prev phase-B reads done before overwrite
        // ---- stage tile: global f32 -> bf16 hi/lo planes ----
        #pragma unroll
        for (int u = 0; u < 8; ++u) {
            int f = u * 256 + t;
            float4 v = zg[tt * 2048 + f];
            int r = f >> 4, cb = (f & 15) * 4;
            unsigned short h0 = f2bf(v.x), h1 = f2bf(v.y), h2 = f2bf(v.z), h3 = f2bf(v.w);
            *(u16x4*)&zhl[0][r][cb] = (u16x4){h0, h1, h2, h3};
            *(u16x4*)&zhl[1][r][cb] = (u16x4){f2bf(v.x - bf2f(h0)), f2bf(v.y - bf2f(h1)),
                                              f2bf(v.z - bf2f(h2)), f2bf(v.w - bf2f(h3))};
        }
        __syncthreads();

        // ---- phase A: logits via MFMA (3-product bf16 split) ----
        f32x4 acc[2][2];
        #pragma unroll
        for (int rt = 0; rt < 2; ++rt) {
            acc[rt][0] = (f32x4){bias0, bias0, bias0, bias0};
            acc[rt][1] = (f32x4){bias1, bias1, bias1, bias1};
        }
        #pragma unroll
        for (int ks = 0; ks < 2; ++ks) {
            int kc = ks * 32 + lg4 * 8;
            s16x8 bh0 = *(const s16x8*)&mhl[0][ln][kc];
            s16x8 bl0 = *(const s16x8*)&mhl[1][ln][kc];
            s16x8 bh1 = *(const s16x8*)&mhl[0][16 + ln][kc];
            s16x8 bl1 = *(const s16x8*)&mhl[1][16 + ln][kc];
            #pragma unroll
            for (int rt = 0; rt < 2; ++rt) {
                int arow = q * 32 + rt * 16 + ln;
                s16x8 ah = *(const s16x8*)&zhl[0][arow][kc];
                s16x8 al = *(const s16x8*)&zhl[1][arow][kc];
                acc[rt][0] = MFMA_BF16(ah, bh0, acc[rt][0], 0, 0, 0);
                acc[rt][0] = MFMA_BF16(ah, bl0, acc[rt][0], 0, 0, 0);
                acc[rt][0] = MFMA_BF16(al, bh0, acc[rt][0], 0, 0, 0);
                acc[rt][1] = MFMA_BF16(ah, bh1, acc[rt][1], 0, 0, 0);
                acc[rt][1] = MFMA_BF16(ah, bl1, acc[rt][1], 0, 0, 0);
                acc[rt][1] = MFMA_BF16(al, bh1, acc[rt][1], 0, 0, 0);
            }
        }
        // ---- softmax over k (16-lane groups; k>=20 masked) ----
        #pragma unroll
        for (int rt = 0; rt < 2; ++rt) {
            #pragma unroll
            for (int rg = 0; rg < 4; ++rg) {
                float v0 = acc[rt][0][rg];
                float v1 = (ln < 4) ? acc[rt][1][rg] : -INFINITY;
                float m = fmaxf(v0, v1);
                m = fmaxf(m, __shfl_xor(m, 1));
                m = fmaxf(m, __shfl_xor(m, 2));
                m = fmaxf(m, __shfl_xor(m, 4));
                m = fmaxf(m, __shfl_xor(m, 8));
                float e0 = __expf(v0 - m);
                float e1 = (ln < 4) ? __expf(v1 - m) : 0.f;
                float s = e0 + e1;
                s += __shfl_xor(s, 1);
                s += __shfl_xor(s, 2);
                s += __shfl_xor(s, 4);
                s += __shfl_xor(s, 8);
                float inv = 1.0f / s;
                float p0 = e0 * inv;
                float p1 = e1 * inv;
                nk0 += p0;
                nk1 += p1;
                int row = q * 32 + rt * 16 + lg4 * 4 + rg;
                pt[row][ln] = p0;
                if (ln < 4) pt[row][16 + ln] = p1;
            }
        }
        __syncthreads();
        // ---- phase B: wave q accumulates rows q*32..+31, lane = column ----
        int rb = q * 32;
        #pragma unroll 4
        for (int r = rb; r < rb + 32; ++r) {
            float zv = bf2f(zhl[0][r][lane]);
            const f32x4* prow = (const f32x4*)&pt[r][0];
            #pragma unroll
            for (int kb = 0; kb < 5; ++kb) {
                f32x4 p = prow[kb];
                pacc[kb * 4 + 0] += p[0] * zv;
                pacc[kb * 4 + 1] += p[1] * zv;
                pacc[kb * 4 + 2] += p[2] * zv;
                pacc[kb * 4 + 3] += p[3] * zv;
            }
        }
    }
    __syncthreads();   // all phase-B reads done before reuse of zhl as scratch

    // ---- cross-wave reduce (reuse zhl region), single atomic per slot ----
    float* red = (float*)&zhl[0][0][0];    // 4*20*64 = 5120 floats <= 9216
    #pragma unroll
    for (int k = 0; k < KK; ++k) red[(q * KK + k) * 64 + lane] = pacc[k];
    nk0 += __shfl_xor(nk0, 16);
    nk0 += __shfl_xor(nk0, 32);
    nk1 += __shfl_xor(nk1, 16);
    nk1 += __shfl_xor(nk1, 32);
    if (lane < 16) nkred[q][lane] = nk0;
    if (lane < 4) nkred[q][16 + lane] = nk1;
    __syncthreads();
    for (int idx = t; idx < KK * 64; idx += 256) {
        int k = idx >> 6, l = idx & 63;
        float sum = red[k * 64 + l] + red[(KK + k) * 64 + l]
                  + red[(2 * KK + k) * 64 + l] + red[(3 * KK + k) * 64 + l];
        atomicAdd(&macc[((size_t)b * KK + k) * LL + l], sum);
    }
    if (t < KK) {
        float sum = nkred[0][t] + nkred[1][t] + nkred[2][t] + nkred[3][t];
        atomicAdd(&nk[b * KK + t], sum);
    }
}

// Per (b,k): pi = Nk/N, mean = (macc/Nk) @ M, bias for next iter, re-zero acc.
__global__ __launch_bounds__(64) void k_final(const float* __restrict__ Mm,
                                              const float* __restrict__ IA,
                                              float* __restrict__ nk,
                                              float* __restrict__ macc,
                                              float* __restrict__ bias,
                                              float* __restrict__ out_pi,
                                              float* __restrict__ out_mean,
                                              float* __restrict__ out_trace) {
    int k = blockIdx.x, b = blockIdx.y;
    int l = threadIdx.x;
    int bk = b * KK + k;
    __shared__ float sraw[64];
    __shared__ float smean[64];
    float Nk = nk[bk];
    if (Nk == 0.f) Nk = 1e-22f;
    float pi = Nk / (float)NN;
    float raw = macc[(size_t)bk * LL + l] / Nk;
    sraw[l] = raw;
    __syncthreads();
    float nm = 0.f;
    #pragma unroll 8
    for (int m = 0; m < 64; ++m) nm += sraw[m] * Mm[m * 64 + l];
    out_mean[(size_t)bk * LL + l] = nm;
    smean[l] = nm;
    __syncthreads();
    float cm = 0.f;
    #pragma unroll 8
    for (int m = 0; m < 64; ++m) cm += smean[m] * IA[m * 64 + l];
    float sqm = nm * nm;
    float sqc = cm * cm;
    for (int off = 32; off > 0; off >>= 1) {
        sqm += __shfl_down(sqm, off);
        sqc += __shfl_down(sqc, off);
    }
    if (l == 0) {
        bias[bk] = logf(pi) - 0.5f * (sqm + sqc);
        out_pi[bk] = pi;
        out_trace[bk] = 1.0f;
        nk[bk] = 0.f;
    }
    macc[(size_t)bk * LL + l] = 0.f;
}

extern "C" void kernel_launch(void* const* d_in, const int* in_sizes, int n_in,
                              void* d_out, int out_size, void* d_ws, size_t ws_size,
                              hipStream_t stream) {
    const float* z = (const float*)d_in[0];
    const float* A = (const float*)d_in[1];
    const int* idxs = (const int*)d_in[2];

    float* out_pi = (float*)d_out;
    float* out_mean = out_pi + BB * KK;
    float* out_trace = out_mean + (size_t)BB * KK * LL;

    float* ws = (float*)d_ws;
    float* IA = ws;
    float* M = ws + 4096;
    float* bias = ws + 8192;
    float* nk = ws + 9472;
    float* macc = ws + 10752;

    k_setup<<<1, 256, 0, stream>>>(A, IA, M);
    k_init<<<dim3(KK, BB), 64, 0, stream>>>(z, idxs, M, IA, out_mean, bias, nk, macc);
    for (int it = 0; it < 5; ++it) {
        k_empass<<<dim3(CHUNKS, BB), 256, 0, stream>>>(z, out_mean, bias, nk, macc);
        k_final<<<dim3(KK, BB), 64, 0, stream>>>(M, IA, nk, macc, bias, out_pi, out_mean, out_trace);
    }
}

// Round 7
// 350.412 us; speedup vs baseline: 1.6727x; 1.3062x over previous
//
#include <hip/hip_runtime.h>
#include <math.h>

#define BB 64
#define NN 8192
#define LL 64
#define KK 20
#define TILE 128
#define NT 8        // tiles per block
#define CHUNKS 8    // blocks per batch entry: CHUNKS*NT*TILE == NN
#define ZSB 72      // zhl/mhl row stride (ushorts): 144 B
#define ZTS 140     // zT row stride (ushorts): 280 B -> scattered writes ~2-way
#define PTTS 136    // ptT row stride (ushorts): 272 B, 16B-aligned b128 reads
#define AS 132      // aug row stride (floats)
#define TS 68       // iaT row stride

typedef float f32x4 __attribute__((ext_vector_type(4)));
typedef short s16x8 __attribute__((ext_vector_type(8)));
typedef short s16x4 __attribute__((ext_vector_type(4)));
typedef unsigned short u16x4 __attribute__((ext_vector_type(4)));
typedef unsigned short u16x2 __attribute__((ext_vector_type(2)));

#define MFMA_BF16 __builtin_amdgcn_mfma_f32_16x16x32_bf16

__device__ __forceinline__ unsigned short f2bf(float f) {   // RNE fp32->bf16
    unsigned int u = __float_as_uint(f);
    u += 0x7fffu + ((u >> 16) & 1u);
    return (unsigned short)(u >> 16);
}
__device__ __forceinline__ float bf2f(unsigned short h) {
    return __uint_as_float(((unsigned int)h) << 16);
}

// ---------------------------------------------------------------------------
// ws layout (floats): IA @0, M @4096, bias @8192, nk @9472, macc @10752
// ---------------------------------------------------------------------------

// IA = I - A ; M = inv(I + IA @ IA^T), Gauss-Jordan (SPD, no pivoting).
__global__ __launch_bounds__(256) void k_setup(const float* __restrict__ A,
                                               float* __restrict__ IA,
                                               float* __restrict__ M) {
    __shared__ __align__(16) float iaT[64][TS];
    __shared__ __align__(16) float aug[64][AS];
    __shared__ __align__(16) float prow[AS];
    int t = threadIdx.x;
    for (int i = t; i < 4096; i += 256) {
        int r = i >> 6, c = i & 63;
        float v = (r == c ? 1.0f : 0.0f) - A[i];
        IA[i] = v;
        iaT[c][r] = v;
    }
    __syncthreads();
    {   // S = I + IA·IAᵀ, 4x4 blocks per thread
        int r0 = (t >> 4) << 2;
        int c0 = (t & 15) << 2;
        float s[4][4];
        #pragma unroll
        for (int a = 0; a < 4; ++a)
            #pragma unroll
            for (int bq = 0; bq < 4; ++bq) s[a][bq] = 0.f;
        for (int l = 0; l < 64; ++l) {
            float4 u = *(const float4*)&iaT[l][r0];
            float4 v = *(const float4*)&iaT[l][c0];
            float uu[4] = {u.x, u.y, u.z, u.w};
            float vv[4] = {v.x, v.y, v.z, v.w};
            #pragma unroll
            for (int a = 0; a < 4; ++a)
                #pragma unroll
                for (int bq = 0; bq < 4; ++bq) s[a][bq] += uu[a] * vv[bq];
        }
        #pragma unroll
        for (int a = 0; a < 4; ++a) {
            int r = r0 + a;
            float4 w;
            w.x = s[a][0] + (r == c0 + 0 ? 1.f : 0.f);
            w.y = s[a][1] + (r == c0 + 1 ? 1.f : 0.f);
            w.z = s[a][2] + (r == c0 + 2 ? 1.f : 0.f);
            w.w = s[a][3] + (r == c0 + 3 ? 1.f : 0.f);
            *(float4*)&aug[r][c0] = w;
            float4 id;
            id.x = (r == c0 + 0 ? 1.f : 0.f);
            id.y = (r == c0 + 1 ? 1.f : 0.f);
            id.z = (r == c0 + 2 ? 1.f : 0.f);
            id.w = (r == c0 + 3 ? 1.f : 0.f);
            *(float4*)&aug[r][64 + c0] = id;
        }
    }
    __syncthreads();
    int r = t & 63;
    int cbase = (t >> 6) * 32;
    for (int k = 0; k < 64; ++k) {
        float pivinv = 1.0f / aug[k][k];
        float f = aug[r][k];
        if (r == k) {
            #pragma unroll
            for (int i = 0; i < 8; ++i) {
                float4 v = *(const float4*)&aug[k][cbase + 4 * i];
                v.x *= pivinv; v.y *= pivinv; v.z *= pivinv; v.w *= pivinv;
                *(float4*)&prow[cbase + 4 * i] = v;
            }
        }
        __syncthreads();
        if (r != k) {
            #pragma unroll
            for (int i = 0; i < 8; ++i) {
                float4 p = *(const float4*)&prow[cbase + 4 * i];
                float4 v = *(const float4*)&aug[r][cbase + 4 * i];
                v.x -= f * p.x; v.y -= f * p.y; v.z -= f * p.z; v.w -= f * p.w;
                *(float4*)&aug[r][cbase + 4 * i] = v;
            }
        } else {
            #pragma unroll
            for (int i = 0; i < 8; ++i)
                *(float4*)&aug[k][cbase + 4 * i] = *(const float4*)&prow[cbase + 4 * i];
        }
        __syncthreads();
    }
    for (int i = t; i < 4096; i += 256) {
        int rr = i >> 6, c = i & 63;
        M[i] = aug[rr][64 + c];
    }
}

// Per (b,k): mean = z[b, idx, :] @ M ; write bias; zero accumulators.
__global__ __launch_bounds__(64) void k_init(const float* __restrict__ z,
                                             const int* __restrict__ idxs,
                                             const float* __restrict__ M,
                                             const float* __restrict__ IA,
                                             float* __restrict__ out_mean,
                                             float* __restrict__ bias,
                                             float* __restrict__ nk,
                                             float* __restrict__ macc) {
    int k = blockIdx.x, b = blockIdx.y;
    int l = threadIdx.x;
    int bk = b * KK + k;
    __shared__ float srow[64];
    __shared__ float smean[64];
    int idx = idxs[bk];
    srow[l] = z[((size_t)b * NN + idx) * LL + l];
    __syncthreads();
    float nm = 0.f;
    #pragma unroll 8
    for (int m = 0; m < 64; ++m) nm += srow[m] * M[m * 64 + l];
    out_mean[(size_t)bk * LL + l] = nm;
    smean[l] = nm;
    __syncthreads();
    float cm = 0.f;
    #pragma unroll 8
    for (int m = 0; m < 64; ++m) cm += smean[m] * IA[m * 64 + l];
    float sqm = nm * nm;
    float sqc = cm * cm;
    for (int off = 32; off > 0; off >>= 1) {
        sqm += __shfl_down(sqm, off);
        sqc += __shfl_down(sqc, off);
    }
    if (l == 0) {
        bias[bk] = logf(1.0f / KK) - 0.5f * (sqm + sqc);
        nk[bk] = 0.f;
    }
    macc[(size_t)bk * LL + l] = 0.f;
}

// Fused EM pass. Phase A: logits via MFMA (bf16 hi/lo split) + in-register
// softmax -> ptT (bf16). Phase B: macc-tile via MFMA (A = ptT, B = zT),
// accumulators carried in VGPRs across all NT tiles; wave q owns cols
// 16q..16q+15 so no cross-wave reduce. One atomic per output element.
__global__ __launch_bounds__(256, 2) void k_empass(const float* __restrict__ z,
                                                   const float* __restrict__ mean,
                                                   const float* __restrict__ bias,
                                                   float* __restrict__ nk,
                                                   float* __restrict__ macc) {
    __shared__ __align__(16) unsigned short zhl[2][TILE][ZSB];   // z hi/lo, row-major
    __shared__ __align__(16) unsigned short mhl[2][32][ZSB];     // mean hi/lo, rows 20-31 zero
    __shared__ __align__(16) unsigned short zT[64][ZTS];         // z hi, col-major
    __shared__ __align__(16) unsigned short ptT[32][PTTS];       // posteriors [comp][row], rows 20-31 zero
    __shared__ float bias_s[KK];
    __shared__ float nkred[4][KK];
    int t = threadIdx.x;
    int lane = t & 63;
    int q = t >> 6;             // wave id 0..3
    int ln = lane & 15;
    int lg4 = lane >> 4;        // 0..3
    int s = t & 15;             // col-quad for staging
    int b = blockIdx.y;
    size_t zbase = ((size_t)b * NN + (size_t)blockIdx.x * (TILE * NT)) * LL;

    // stage mean (split hi/lo) + zero pads + bias; zero ptT comp rows 20..31
    for (int i = t; i < KK * LL; i += 256) {
        float f = mean[(size_t)b * KK * LL + i];
        int k = i >> 6, c = i & 63;
        unsigned short h = f2bf(f);
        mhl[0][k][c] = h;
        mhl[1][k][c] = f2bf(f - bf2f(h));
    }
    for (int i = 20 * ZSB + t; i < 32 * ZSB; i += 256) {
        (&mhl[0][0][0])[i] = 0;
        (&mhl[1][0][0])[i] = 0;
    }
    {
        unsigned int* pz = (unsigned int*)&ptT[20][0];
        for (int i = t; i < 6 * PTTS; i += 256) pz[i] = 0;   // 12*PTTS ushorts
    }
    if (t < KK) bias_s[t] = bias[b * KK + t];
    __syncthreads();
    float bias0 = bias_s[ln];
    float bias1 = (ln < 4) ? bias_s[16 + ln] : 0.f;

    const float4* zg = (const float4*)(z + zbase);
    f32x4 bacc0 = {0.f, 0.f, 0.f, 0.f};
    f32x4 bacc1 = {0.f, 0.f, 0.f, 0.f};
    float nk0 = 0.f, nk1 = 0.f;

    for (int tt = 0; tt < NT; ++tt) {
        if (tt > 0) __syncthreads();   // prev phase-B reads done before overwrite
        // ---- stage: thread loads rows r0,r0+1 x cols 4s..4s+3 ----
        #pragma unroll
        for (int u = 0; u < 4; ++u) {
            int r0 = u * 32 + ((t >> 4) << 1);
            float4 v0 = zg[tt * 2048 + r0 * 16 + s];
            float4 v1 = zg[tt * 2048 + (r0 + 1) * 16 + s];
            unsigned short h0 = f2bf(v0.x), h1 = f2bf(v0.y), h2 = f2bf(v0.z), h3 = f2bf(v0.w);
            unsigned short g0 = f2bf(v1.x), g1 = f2bf(v1.y), g2 = f2bf(v1.z), g3 = f2bf(v1.w);
            *(u16x4*)&zhl[0][r0][4 * s]     = (u16x4){h0, h1, h2, h3};
            *(u16x4*)&zhl[0][r0 + 1][4 * s] = (u16x4){g0, g1, g2, g3};
            *(u16x4*)&zhl[1][r0][4 * s]     = (u16x4){f2bf(v0.x - bf2f(h0)), f2bf(v0.y - bf2f(h1)),
                                                      f2bf(v0.z - bf2f(h2)), f2bf(v0.w - bf2f(h3))};
            *(u16x4*)&zhl[1][r0 + 1][4 * s] = (u16x4){f2bf(v1.x - bf2f(g0)), f2bf(v1.y - bf2f(g1)),
                                                      f2bf(v1.z - bf2f(g2)), f2bf(v1.w - bf2f(g3))};
            *(u16x2*)&zT[4 * s + 0][r0] = (u16x2){h0, g0};
            *(u16x2*)&zT[4 * s + 1][r0] = (u16x2){h1, g1};
            *(u16x2*)&zT[4 * s + 2][r0] = (u16x2){h2, g2};
            *(u16x2*)&zT[4 * s + 3][r0] = (u16x2){h3, g3};
        }
        __syncthreads();

        // ---- phase A: logits via MFMA (3-product bf16 split) ----
        f32x4 acc[2][2];
        #pragma unroll
        for (int rt = 0; rt < 2; ++rt) {
            acc[rt][0] = (f32x4){bias0, bias0, bias0, bias0};
            acc[rt][1] = (f32x4){bias1, bias1, bias1, bias1};
        }
        #pragma unroll
        for (int ks = 0; ks < 2; ++ks) {
            int kc = ks * 32 + lg4 * 8;
            s16x8 bh0 = *(const s16x8*)&mhl[0][ln][kc];
            s16x8 bl0 = *(const s16x8*)&mhl[1][ln][kc];
            s16x8 bh1 = *(const s16x8*)&mhl[0][16 + ln][kc];
            s16x8 bl1 = *(const s16x8*)&mhl[1][16 + ln][kc];
            #pragma unroll
            for (int rt = 0; rt < 2; ++rt) {
                int arow = q * 32 + rt * 16 + ln;
                s16x8 ah = *(const s16x8*)&zhl[0][arow][kc];
                s16x8 al = *(const s16x8*)&zhl[1][arow][kc];
                acc[rt][0] = MFMA_BF16(ah, bh0, acc[rt][0], 0, 0, 0);
                acc[rt][0] = MFMA_BF16(ah, bl0, acc[rt][0], 0, 0, 0);
                acc[rt][0] = MFMA_BF16(al, bh0, acc[rt][0], 0, 0, 0);
                acc[rt][1] = MFMA_BF16(ah, bh1, acc[rt][1], 0, 0, 0);
                acc[rt][1] = MFMA_BF16(ah, bl1, acc[rt][1], 0, 0, 0);
                acc[rt][1] = MFMA_BF16(al, bh1, acc[rt][1], 0, 0, 0);
            }
        }
        // ---- softmax over k (16-lane groups; k>=20 masked) -> ptT bf16 ----
        #pragma unroll
        for (int rt = 0; rt < 2; ++rt) {
            #pragma unroll
            for (int rg = 0; rg < 4; ++rg) {
                float v0 = acc[rt][0][rg];
                float v1 = (ln < 4) ? acc[rt][1][rg] : -INFINITY;
                float m = fmaxf(v0, v1);
                m = fmaxf(m, __shfl_xor(m, 1));
                m = fmaxf(m, __shfl_xor(m, 2));
                m = fmaxf(m, __shfl_xor(m, 4));
                m = fmaxf(m, __shfl_xor(m, 8));
                float e0 = __expf(v0 - m);
                float e1 = (ln < 4) ? __expf(v1 - m) : 0.f;
                float sm = e0 + e1;
                sm += __shfl_xor(sm, 1);
                sm += __shfl_xor(sm, 2);
                sm += __shfl_xor(sm, 4);
                sm += __shfl_xor(sm, 8);
                float inv = 1.0f / sm;
                float p0 = e0 * inv;
                float p1 = e1 * inv;
                nk0 += p0;
                nk1 += p1;
                int row = q * 32 + rt * 16 + lg4 * 4 + rg;
                ptT[ln][row] = f2bf(p0);
                if (ln < 4) ptT[16 + ln][row] = f2bf(p1);
            }
        }
        __syncthreads();

        // ---- phase B: macc-tile MFMA; wave q -> cols 16q..16q+15 ----
        #pragma unroll
        for (int ch = 0; ch < 4; ++ch) {
            int rr = ch * 32 + lg4 * 8;
            s16x4 zb0 = *(const s16x4*)&zT[q * 16 + ln][rr];
            s16x4 zb1 = *(const s16x4*)&zT[q * 16 + ln][rr + 4];
            s16x8 bfr = (s16x8){zb0[0], zb0[1], zb0[2], zb0[3], zb1[0], zb1[1], zb1[2], zb1[3]};
            s16x8 af0 = *(const s16x8*)&ptT[ln][rr];
            s16x8 af1 = *(const s16x8*)&ptT[16 + ln][rr];
            bacc0 = MFMA_BF16(af0, bfr, bacc0, 0, 0, 0);
            bacc1 = MFMA_BF16(af1, bfr, bacc1, 0, 0, 0);
        }
    }

    // ---- Nk reduce (per-wave over lg4 groups) ----
    nk0 += __shfl_xor(nk0, 16);
    nk0 += __shfl_xor(nk0, 32);
    nk1 += __shfl_xor(nk1, 16);
    nk1 += __shfl_xor(nk1, 32);
    if (lane < 16) nkred[q][lane] = nk0;
    if (lane < 4) nkred[q][16 + lane] = nk1;

    // ---- macc write: D col = lane&15 -> col 16q+ln; row = lg4*4+reg -> comp ----
    int col = q * 16 + ln;
    #pragma unroll
    for (int reg = 0; reg < 4; ++reg) {
        int comp = lg4 * 4 + reg;
        atomicAdd(&macc[((size_t)b * KK + comp) * LL + col], bacc0[reg]);
    }
    if (lg4 == 0) {
        #pragma unroll
        for (int reg = 0; reg < 4; ++reg)
            atomicAdd(&macc[((size_t)b * KK + 16 + reg) * LL + col], bacc1[reg]);
    }
    __syncthreads();
    if (t < KK) {
        float sum = nkred[0][t] + nkred[1][t] + nkred[2][t] + nkred[3][t];
        atomicAdd(&nk[b * KK + t], sum);
    }
}

// Per (b,k): pi = Nk/N, mean = (macc/Nk) @ M, bias for next iter, re-zero acc.
__global__ __launch_bounds__(64) void k_final(const float* __restrict__ Mm,
                                              const float* __restrict__ IA,
                                              float* __restrict__ nk,
                                              float* __restrict__ macc,
                                              float* __restrict__ bias,
                                              float* __restrict__ out_pi,
                                              float* __restrict__ out_mean,
                                              float* __restrict__ out_trace) {
    int k = blockIdx.x, b = blockIdx.y;
    int l = threadIdx.x;
    int bk = b * KK + k;
    __shared__ float sraw[64];
    __shared__ float smean[64];
    float Nk = nk[bk];
    if (Nk == 0.f) Nk = 1e-22f;
    float pi = Nk / (float)NN;
    float raw = macc[(size_t)bk * LL + l] / Nk;
    sraw[l] = raw;
    __syncthreads();
    float nm = 0.f;
    #pragma unroll 8
    for (int m = 0; m < 64; ++m) nm += sraw[m] * Mm[m * 64 + l];
    out_mean[(size_t)bk * LL + l] = nm;
    smean[l] = nm;
    __syncthreads();
    float cm = 0.f;
    #pragma unroll 8
    for (int m = 0; m < 64; ++m) cm += smean[m] * IA[m * 64 + l];
    float sqm = nm * nm;
    float sqc = cm * cm;
    for (int off = 32; off > 0; off >>= 1) {
        sqm += __shfl_down(sqm, off);
        sqc += __shfl_down(sqc, off);
    }
    if (l == 0) {
        bias[bk] = logf(pi) - 0.5f * (sqm + sqc);
        out_pi[bk] = pi;
        out_trace[bk] = 1.0f;
        nk[bk] = 0.f;
    }
    macc[(size_t)bk * LL + l] = 0.f;
}

extern "C" void kernel_launch(void* const* d_in, const int* in_sizes, int n_in,
                              void* d_out, int out_size, void* d_ws, size_t ws_size,
                              hipStream_t stream) {
    const float* z = (const float*)d_in[0];
    const float* A = (const float*)d_in[1];
    const int* idxs = (const int*)d_in[2];

    float* out_pi = (float*)d_out;
    float* out_mean = out_pi + BB * KK;
    float* out_trace = out_mean + (size_t)BB * KK * LL;

    float* ws = (float*)d_ws;
    float* IA = ws;
    float* M = ws + 4096;
    float* bias = ws + 8192;
    float* nk = ws + 9472;
    float* macc = ws + 10752;

    k_setup<<<1, 256, 0, stream>>>(A, IA, M);
    k_init<<<dim3(KK, BB), 64, 0, stream>>>(z, idxs, M, IA, out_mean, bias, nk, macc);
    for (int it = 0; it < 5; ++it) {
        k_empass<<<dim3(CHUNKS, BB), 256, 0, stream>>>(z, out_mean, bias, nk, macc);
        k_final<<<dim3(KK, BB), 64, 0, stream>>>(M, IA, nk, macc, bias, out_pi, out_mean, out_trace);
    }
}